// Round 5
// baseline (35076.999 us; speedup 1.0000x reference)
//
#include <hip/hip_runtime.h>
#include <math.h>

#define BB 64
#define TT 128
#define DBX 256
#define IND 264
#define HS 512
#define NH 4
#define MMM 128
#define AAA 2048
#define PPH 390
#define NCOLS (DBX + NH*PPH)   // 2072
#define KTOT (IND + HS + HS)   // 1288
#define KSPL 8                 // k1 split-K: 8 x 161
#define KCH  161
#define EPSF 1e-8f

__device__ __forceinline__ float sigmf(float x){ return 1.0f/(1.0f+expf(-x)); }
__device__ __forceinline__ float softplusf(float x){ return (x > 20.0f) ? x : log1pf(expf(x)); }

// ---------------- init ----------------
__global__ void k_init(float* __restrict__ hT, float* __restrict__ readT,
                       float* __restrict__ wt, float* __restrict__ mem){
  int i = blockIdx.x*blockDim.x + threadIdx.x;
  int stride = gridDim.x*blockDim.x;
  for (int idx=i; idx<BB*MMM*AAA; idx+=stride) mem[idx]=0.01f;
  for (int idx=i; idx<HS*BB; idx+=stride){ hT[idx]=1.0f; readT[idx]=0.01f; }
  for (int idx=i; idx<BB*NH*AAA; idx+=stride) wt[idx] = ((idx & (AAA-1))==0)?1.0f:0.0f;
}

// ---------------- transpose x[b][t][i] -> xT[t*IND+i][b] (once) ----------------
__global__ __launch_bounds__(256) void k_tx(const float* __restrict__ x, float* __restrict__ xT){
  int b = blockIdx.x;
  for (int f = threadIdx.x; f < TT*IND; f += 256)
    xT[(size_t)f*BB + b] = x[(size_t)b*TT*IND + f];
}

__device__ __forceinline__ float act_load(const float* __restrict__ xt,
                                          const float* __restrict__ hT,
                                          const float* __restrict__ rT,
                                          int k, int lane){
  if (k < IND)            return xt[(size_t)k*BB + lane];
  else if (k < IND+HS)    return hT[(k-IND)*BB + lane];
  else                    return rT[(k-IND-HS)*BB + lane];
}

// ---------------- k1: split-K partial GEMM  hpart[ks][j][b] ----------------
// grid (32, 8), block 256 = 4 waves x 4 cols. lane = b. K-chunk of 161.
__global__ __launch_bounds__(256) void k1_state(
    const float* __restrict__ xT, const float* __restrict__ Wst,
    const float* __restrict__ hTp, const float* __restrict__ readTp,
    float* __restrict__ hpart, float* __restrict__ wcsum, float* __restrict__ wpsum, int t)
{
  int tid = threadIdx.x, wave = tid>>6, lane = tid&63;
  int ks = blockIdx.y;
  int j0 = blockIdx.x*16 + wave*4;
  if (blockIdx.x==0 && ks==0){
    wcsum[tid] = 0.0f;   // BB*NH == 256
    wpsum[tid] = 0.0f;
  }
  const float* xt = xT + (size_t)t*IND*BB;
  float a0=0,a1=0,a2=0,a3=0;
  int k0 = ks*KCH, kend = k0+KCH;

  for (int kb=k0; kb<kend; kb+=8){
    int n = kend-kb; n = n>8?8:n;
    float av[8]; float4 wv[8];
    #pragma unroll
    for (int u=0; u<8; ++u){
      if (u<n){
        int k = kb+u;
        av[u] = act_load(xt, hTp, readTp, k, lane);
        wv[u] = *(const float4*)(Wst + (size_t)k*HS + j0);
      }
    }
    #pragma unroll
    for (int u=0; u<8; ++u){
      if (u<n){
        a0 += av[u]*wv[u].x; a1 += av[u]*wv[u].y;
        a2 += av[u]*wv[u].z; a3 += av[u]*wv[u].w;
      }
    }
  }

  float* hp = hpart + (size_t)ks*HS*BB + (size_t)j0*BB + lane;
  hp[0]    = a0;
  hp[BB]   = a1;
  hp[2*BB] = a2;
  hp[3*BB] = a3;
}

// ---------------- k2h: reduce split-K partials -> h = sigmoid(. + b) ----------------
__global__ __launch_bounds__(512) void k2h(
    const float* __restrict__ hpart, const float* __restrict__ bst, float* __restrict__ hTn)
{
  int idx = blockIdx.x*512 + threadIdx.x;   // 64 blocks x 512 = 32768 = HS*BB
  float pv[KSPL];
  #pragma unroll
  for (int ks=0; ks<KSPL; ++ks) pv[ks] = hpart[(size_t)ks*HS*BB + idx];
  float v = 0.0f;
  #pragma unroll
  for (int ks=0; ks<KSPL; ++ks) v += pv[ks];
  hTn[idx] = sigmf(v + bst[idx>>6]);
}

// ---------------- k2: out/upd GEMM, split-K across 4 waves, + transforms ----------------
// grid 259 blocks, block 256. Block owns 8 cols; wave = K-chunk of 128.
__global__ __launch_bounds__(256) void k2_outupd(
    const float* __restrict__ hTn,
    const float* __restrict__ Wout, const float* __restrict__ bout,
    const float* __restrict__ Wupd, const float* __restrict__ bupd,
    float* __restrict__ out,
    float* __restrict__ kvec_t, float* __restrict__ beta, float* __restrict__ gbuf,
    float* __restrict__ gam, float* __restrict__ shraw,
    float* __restrict__ erase, float* __restrict__ addb, int t)
{
  __shared__ float part[4][8][BB];
  int tid = threadIdx.x, ks = tid>>6, lane = tid&63;
  int c0 = blockIdx.x*8;
  bool isout = (c0 < DBX);                 // DBX%8==0: no straddle
  size_t strd = isout ? (size_t)DBX : (size_t)(NH*PPH);
  const float* wbase = isout ? (Wout + c0) : (Wupd + (c0 - DBX));
  bool valid = (c0 < NCOLS);

  float acc[8] = {0,0,0,0,0,0,0,0};
  if (valid){
    int k0 = ks*128;
    for (int kb=k0; kb<k0+128; kb+=4){
      float av[4]; float4 w0[4], w1[4];
      #pragma unroll
      for (int u=0; u<4; ++u){
        int k = kb+u;
        av[u] = hTn[k*BB + lane];
        const float4* w4 = (const float4*)(wbase + (size_t)k*strd);
        w0[u] = w4[0]; w1[u] = w4[1];
      }
      #pragma unroll
      for (int u=0; u<4; ++u){
        acc[0]+=av[u]*w0[u].x; acc[1]+=av[u]*w0[u].y; acc[2]+=av[u]*w0[u].z; acc[3]+=av[u]*w0[u].w;
        acc[4]+=av[u]*w1[u].x; acc[5]+=av[u]*w1[u].y; acc[6]+=av[u]*w1[u].z; acc[7]+=av[u]*w1[u].w;
      }
    }
  }
  #pragma unroll
  for (int u=0; u<8; ++u) part[ks][u][lane] = acc[u];
  __syncthreads();
  if (!valid) return;

  for (int idx=tid; idx<8*BB; idx+=256){
    int u = idx>>6, b = idx&63;
    int c = c0+u;
    float v = part[0][u][b] + part[1][u][b] + part[2][u][b] + part[3][u][b];
    if (isout){
      out[((size_t)b*TT + t)*DBX + c] = sigmf(v + bout[c]);
    } else {
      int u2 = c - DBX;
      int hh = u2 / PPH;
      int p  = u2 - hh*PPH;
      v += bupd[u2];
      if (p < MMM)            kvec_t[b*HS + p*NH + hh] = v;
      else if (p == MMM)      beta[b*NH+hh] = softplusf(v);
      else if (p == MMM+1)    gbuf[b*NH+hh] = sigmf(v);
      else if (p <  MMM+5)    shraw[(b*NH+hh)*3 + (p-(MMM+2))] = v;
      else if (p == MMM+5)    gam[b*NH+hh] = 1.0f + softplusf(v);
      else if (p <  2*MMM+6)  erase[b*HS + hh*MMM + (p-(MMM+6))] = sigmf(v);
      else                    addb[b*HS + hh*MMM + (p-(2*MMM+6))] = tanhf(v);
    }
  }
}

// ---------------- content dots + knorm + mnorm + exp(beta*sim) ----------------
__global__ __launch_bounds__(512) void k_dots(
    const float* __restrict__ mem, const float* __restrict__ kvec_t,
    const float* __restrict__ beta,
    float* __restrict__ ebuf, float* __restrict__ wcsum, float* __restrict__ readTn)
{
  int b = blockIdx.x, s = blockIdx.y, tid = threadIdx.x;
  __shared__ __align__(16) float klt[HS];   // [m][h]
  __shared__ float red[HS];
  __shared__ float kn[NH];
  __shared__ float rsum[8*NH];
  klt[tid] = kvec_t[b*HS + tid];
  if (s == 0) readTn[(size_t)tid*BB + b] = 0.0f;  // zero next-step read accumulator
  __syncthreads();
  red[tid] = klt[tid]*klt[tid];
  __syncthreads();
  #pragma unroll
  for (int off=256; off>=4; off>>=1){
    if (tid < off) red[tid] += red[tid+off];
    __syncthreads();
  }
  if (tid < NH) kn[tid] = sqrtf(red[tid]);
  __syncthreads();

  int a = s*512 + tid;
  const float* mp = mem + (size_t)b*MMM*AAA + a;
  const float4* k4 = (const float4*)klt;
  float a0=0,a1=0,a2=0,a3=0,n2=0;
  for (int mb=0; mb<MMM; mb+=32){
    float mv[32];
    #pragma unroll
    for (int u=0; u<32; ++u) mv[u] = mp[(size_t)(mb+u)*AAA];
    #pragma unroll
    for (int u=0; u<32; ++u){
      float4 kv = k4[mb+u];
      a0 += kv.x*mv[u]; a1 += kv.y*mv[u]; a2 += kv.z*mv[u]; a3 += kv.w*mv[u];
      n2 += mv[u]*mv[u];
    }
  }
  float mn = sqrtf(n2);
  float acc[NH] = {a0,a1,a2,a3};
  int wid = tid >> 6, lane = tid & 63;
  #pragma unroll
  for (int hh=0; hh<NH; ++hh){
    float sim = acc[hh]/(kn[hh]*mn + EPSF);
    float e = expf(beta[b*NH+hh]*sim);
    ebuf[((size_t)(b*NH+hh))*AAA + a] = e;
    float v = e;
    #pragma unroll
    for (int off=32; off>0; off>>=1) v += __shfl_xor(v, off);
    if (lane==0) rsum[wid*NH+hh] = v;
  }
  __syncthreads();
  if (tid < NH){
    float s2 = 0.0f;
    #pragma unroll
    for (int w=0; w<8; ++w) s2 += rsum[w*NH+tid];
    atomicAdd(&wcsum[b*NH+tid], s2);
  }
}

// ---------------- normalize + interpolate + shift + sharpen ----------------
__global__ __launch_bounds__(512) void k_shift(
    const float* __restrict__ ebuf, const float* __restrict__ wcsum,
    const float* __restrict__ gbuf, const float* __restrict__ shraw,
    const float* __restrict__ gam, const float* __restrict__ wt,
    float* __restrict__ wpb, float* __restrict__ wpsum)
{
  int b = blockIdx.x, s = blockIdx.y, tid = threadIdx.x;
  int a = s*512 + tid;
  int am1 = (a + AAA - 1) & (AAA-1);
  int ap1 = (a + 1) & (AAA-1);
  __shared__ float sh[NH*3], gl[NH], gml[NH], winv[NH];
  __shared__ float rsum[8*NH];
  if (tid < NH){
    int hh = tid;
    float s0=shraw[(b*NH+hh)*3], s1=shraw[(b*NH+hh)*3+1], s2=shraw[(b*NH+hh)*3+2];
    float mx = fmaxf(s0, fmaxf(s1, s2));
    float e0=expf(s0-mx), e1=expf(s1-mx), e2=expf(s2-mx);
    float inv = 1.0f/(e0+e1+e2);
    sh[hh*3+0]=e0*inv; sh[hh*3+1]=e1*inv; sh[hh*3+2]=e2*inv;
    gl[hh]  = gbuf[b*NH+hh];
    gml[hh] = gam[b*NH+hh];
    winv[hh]= 1.0f/wcsum[b*NH+hh];
  }
  __syncthreads();
  int wid = tid >> 6, lane = tid & 63;
  #pragma unroll
  for (int hh=0; hh<NH; ++hh){
    const float* eb = ebuf + ((size_t)(b*NH+hh))*AAA;
    const float* wb = wt   + ((size_t)(b*NH+hh))*AAA;
    float inv = winv[hh], g = gl[hh];
    float s0 = sh[hh*3+0], s1 = sh[hh*3+1], s2 = sh[hh*3+2];
    float wgm1 = g*eb[am1]*inv + (1.0f-g)*wb[am1];
    float wg0  = g*eb[a]  *inv + (1.0f-g)*wb[a];
    float wgp1 = g*eb[ap1]*inv + (1.0f-g)*wb[ap1];
    float ws = s0*wgp1 + s1*wg0 + s2*wgm1;
    float wp = powf(ws + EPSF, gml[hh]);
    wpb[((size_t)(b*NH+hh))*AAA + a] = wp;
    float v = wp;
    #pragma unroll
    for (int off=32; off>0; off>>=1) v += __shfl_xor(v, off);
    if (lane==0) rsum[wid*NH+hh] = v;
  }
  __syncthreads();
  if (tid < NH){
    float s3 = 0.0f;
    #pragma unroll
    for (int w=0; w<8; ++w) s3 += rsum[w*NH+tid];
    atomicAdd(&wpsum[b*NH+tid], s3);
  }
}

// ---------------- wt_new + mem update + read einsum ----------------
__global__ __launch_bounds__(512) void k_upd(
    float* __restrict__ mem, const float* __restrict__ wpb, const float* __restrict__ wpsum,
    const float* __restrict__ erase, const float* __restrict__ addb,
    float* __restrict__ wt, float* __restrict__ readTn)
{
  int b = blockIdx.x, s = blockIdx.y, tid = threadIdx.x;
  int a = s*512 + tid;
  __shared__ __align__(16) float ert[HS];      // [m][h]
  __shared__ __align__(16) float adt[HS];      // [m][h]
  __shared__ __align__(16) float wtl[512*NH];  // [col_in_chunk][h], 8KB
  {
    int m = tid & 127, hh = tid >> 7;
    ert[m*NH+hh] = erase[b*HS + hh*MMM + m];
    adt[m*NH+hh] = addb[b*HS + hh*MMM + m];
  }
  float wtn[NH];
  #pragma unroll
  for (int hh=0; hh<NH; ++hh){
    float w = wpb[((size_t)(b*NH+hh))*AAA + a] / wpsum[b*NH+hh];
    wtn[hh] = w;
    wt[((size_t)(b*NH+hh))*AAA + a] = w;
    wtl[tid*NH+hh] = w;
  }
  __syncthreads();

  float* mp = mem + (size_t)b*MMM*AAA + a;
  const float4* e4 = (const float4*)ert;
  const float4* a4 = (const float4*)adt;
  for (int mb=0; mb<MMM; mb+=16){
    float mv[16];
    #pragma unroll
    for (int u=0; u<16; ++u) mv[u] = mp[(size_t)(mb+u)*AAA];
    float outv[16];
    #pragma unroll
    for (int u=0; u<16; ++u){
      float4 ev = e4[mb+u], av = a4[mb+u];
      float et = (1.0f - ev.x*wtn[0]) * (1.0f - ev.y*wtn[1])
               * (1.0f - ev.z*wtn[2]) * (1.0f - ev.w*wtn[3]);
      float at = av.x*wtn[0] + av.y*wtn[1] + av.z*wtn[2] + av.w*wtn[3];
      outv[u] = mv[u]*et + at;
    }
    #pragma unroll
    for (int u=0; u<16; ++u) mp[(size_t)(mb+u)*AAA] = outv[u];
  }
  __syncthreads();

  // phase B: read[h,m] partial over this block's 512-column slice (L2-hot, float4)
  int m = tid >> 2, sl = tid & 3;
  const float4* row4 = (const float4*)(mem + (size_t)b*MMM*AAA + (size_t)m*AAA + s*512 + sl*128);
  const float4* w4 = (const float4*)wtl;
  float r0=0,r1=0,r2=0,r3=0;
  for (int jb=0; jb<32; jb+=8){          // 32 float4 = 128 columns
    float4 rv[8];
    #pragma unroll
    for (int u=0; u<8; ++u) rv[u] = row4[jb+u];
    #pragma unroll
    for (int u=0; u<8; ++u){
      int j = (jb+u)*4;
      float4 wa = w4[sl*128 + j+0];
      float4 wb = w4[sl*128 + j+1];
      float4 wc = w4[sl*128 + j+2];
      float4 wd = w4[sl*128 + j+3];
      r0 += rv[u].x*wa.x + rv[u].y*wb.x + rv[u].z*wc.x + rv[u].w*wd.x;
      r1 += rv[u].x*wa.y + rv[u].y*wb.y + rv[u].z*wc.y + rv[u].w*wd.y;
      r2 += rv[u].x*wa.z + rv[u].y*wb.z + rv[u].z*wc.z + rv[u].w*wd.z;
      r3 += rv[u].x*wa.w + rv[u].y*wb.w + rv[u].z*wc.w + rv[u].w*wd.w;
    }
  }
  float racc[NH] = {r0,r1,r2,r3};
  #pragma unroll
  for (int hh=0; hh<NH; ++hh){
    float v = racc[hh];
    v += __shfl_xor(v, 1);
    v += __shfl_xor(v, 2);
    racc[hh] = v;
  }
  if (sl == 0){
    #pragma unroll
    for (int hh=0; hh<NH; ++hh)
      atomicAdd(&readTn[(size_t)(hh*MMM+m)*BB + b], racc[hh]);
  }
}

extern "C" void kernel_launch(void* const* d_in, const int* in_sizes, int n_in,
                              void* d_out, int out_size, void* d_ws, size_t ws_size,
                              hipStream_t stream){
  const float* x    = (const float*)d_in[0];
  const float* Wst  = (const float*)d_in[1];
  const float* bst  = (const float*)d_in[2];
  const float* Wout = (const float*)d_in[3];
  const float* bout = (const float*)d_in[4];
  const float* Wupd = (const float*)d_in[5];
  const float* bupd = (const float*)d_in[6];
  float* out = (float*)d_out;

  float* p = (float*)d_ws;
  float* hT     = p; p += 2*HS*BB;            // ping-pong h, [j][b]
  float* readT  = p; p += 2*HS*BB;            // ping-pong read, [(h,m)][b]
  float* hpart  = p; p += KSPL*HS*BB;         // split-K partials (1 MB)
  float* xT     = p; p += (size_t)TT*IND*BB;  // transposed x (8.65 MB)
  float* wt     = p; p += BB*NH*AAA;
  float* mem    = p; p += (size_t)BB*MMM*AAA;
  float* kvec_t = p; p += BB*HS;
  float* beta   = p; p += BB*NH;
  float* gbuf   = p; p += BB*NH;
  float* gam    = p; p += BB*NH;
  float* shraw  = p; p += BB*NH*3;
  float* erase  = p; p += BB*HS;
  float* addb   = p; p += BB*HS;
  float* ebuf   = p; p += BB*NH*AAA;
  float* wpb    = p; p += BB*NH*AAA;
  float* wcsum  = p; p += BB*NH;
  float* wpsum  = p; p += BB*NH;

  k_init<<<2048, 256, 0, stream>>>(hT, readT, wt, mem);
  k_tx<<<BB, 256, 0, stream>>>(x, xT);
  for (int t=0; t<TT; ++t){
    const float* hTp = hT    + (t&1)*HS*BB;
    float* hTn       = hT    + ((t+1)&1)*HS*BB;
    const float* rTp = readT + (t&1)*HS*BB;
    float* rTn       = readT + ((t+1)&1)*HS*BB;
    k1_state<<<dim3(32,KSPL), 256, 0, stream>>>(xT, Wst, hTp, rTp, hpart, wcsum, wpsum, t);
    k2h<<<64, 512, 0, stream>>>(hpart, bst, hTn);
    k2_outupd<<<dim3(259), 256, 0, stream>>>(hTn, Wout, bout, Wupd, bupd, out,
        kvec_t, beta, gbuf, gam, shraw, erase, addb, t);
    k_dots<<<dim3(BB,4), 512, 0, stream>>>(mem, kvec_t, beta, ebuf, wcsum, rTn);
    k_shift<<<dim3(BB,4), 512, 0, stream>>>(ebuf, wcsum, gbuf, shraw, gam, wt, wpb, wpsum);
    k_upd<<<dim3(BB,4), 512, 0, stream>>>(mem, wpb, wpsum, erase, addb, wt, rTn);
  }
}

// Round 6
// 11574.322 us; speedup vs baseline: 3.0306x; 3.0306x over previous
//
#include <hip/hip_runtime.h>
#include <math.h>

#define BB 64
#define TT 128
#define DBX 256
#define IND 264
#define HS 512
#define NH 4
#define MMM 128
#define AAA 2048
#define PPH 390
#define NCOLS (DBX + NH*PPH)   // 2072
#define KTOT (IND + HS + HS)   // 1288
#define KSPL 8                 // k1 split-K: 8 x 161
#define KCH  161
#define EPSF 1e-8f

__device__ __forceinline__ float sigmf(float x){ return 1.0f/(1.0f+expf(-x)); }
__device__ __forceinline__ float softplusf(float x){ return (x > 20.0f) ? x : log1pf(expf(x)); }

// ---------------- init ----------------
__global__ void k_init(float* __restrict__ hT, float* __restrict__ readT,
                       float* __restrict__ wt, float* __restrict__ mem){
  int i = blockIdx.x*blockDim.x + threadIdx.x;
  int stride = gridDim.x*blockDim.x;
  for (int idx=i; idx<BB*MMM*AAA; idx+=stride) mem[idx]=0.01f;
  for (int idx=i; idx<HS*BB; idx+=stride){ hT[idx]=1.0f; readT[idx]=0.01f; }
  for (int idx=i; idx<BB*NH*AAA; idx+=stride) wt[idx] = ((idx & (AAA-1))==0)?1.0f:0.0f;
}

// ---------------- transpose x[b][t][i] -> xT[t*IND+i][b] (once) ----------------
__global__ __launch_bounds__(256) void k_tx(const float* __restrict__ x, float* __restrict__ xT){
  int b = blockIdx.x;
  for (int f = threadIdx.x; f < TT*IND; f += 256)
    xT[(size_t)f*BB + b] = x[(size_t)b*TT*IND + f];
}

// ---------------- k1: split-K partial GEMM  hpart[ks][j][b]  (round-4 form) ----------------
__global__ __launch_bounds__(256) void k1_state(
    const float* __restrict__ xT, const float* __restrict__ Wst,
    const float* __restrict__ hTp, const float* __restrict__ readTp,
    float* __restrict__ hpart, float* __restrict__ wcsum, float* __restrict__ wpsum, int t)
{
  int tid = threadIdx.x, wave = tid>>6, lane = tid&63;
  int ks = blockIdx.y;
  int j0 = blockIdx.x*16 + wave*4;
  if (blockIdx.x==0 && ks==0){
    wcsum[tid] = 0.0f;   // BB*NH == 256
    wpsum[tid] = 0.0f;
  }
  float a0=0,a1=0,a2=0,a3=0;
  int k0 = ks*KCH, kend = k0+KCH;

  #define K1STEP(AEXPR) { float aV=(AEXPR); \
      float4 wv = *(const float4*)(Wst + (size_t)k*HS + j0); \
      a0 += aV*wv.x; a1 += aV*wv.y; a2 += aV*wv.z; a3 += aV*wv.w; }

  {int s = k0, e = kend<IND?kend:IND;
   #pragma unroll 4
   for (int k=s;k<e;++k) K1STEP(xT[((size_t)t*IND + k)*BB + lane]); }
  {int s = k0>IND?k0:IND, e = kend<(IND+HS)?kend:(IND+HS);
   #pragma unroll 4
   for (int k=s;k<e;++k) K1STEP(hTp[(k-IND)*BB + lane]); }
  {int s = k0>(IND+HS)?k0:(IND+HS), e = kend;
   #pragma unroll 4
   for (int k=s;k<e;++k) K1STEP(readTp[(k-IND-HS)*BB + lane]); }
  #undef K1STEP

  float* hp = hpart + (size_t)ks*HS*BB + (size_t)j0*BB + lane;
  hp[0]    = a0;
  hp[BB]   = a1;
  hp[2*BB] = a2;
  hp[3*BB] = a3;
}

// ---------------- k2h: reduce split-K partials -> h = sigmoid(. + b) ----------------
__global__ __launch_bounds__(512) void k2h(
    const float* __restrict__ hpart, const float* __restrict__ bst, float* __restrict__ hTn)
{
  int idx = blockIdx.x*512 + threadIdx.x;   // 64 blocks x 512 = 32768 = HS*BB
  float v = 0.0f;
  #pragma unroll
  for (int ks=0; ks<KSPL; ++ks) v += hpart[(size_t)ks*HS*BB + idx];
  hTn[idx] = sigmf(v + bst[idx>>6]);
}

// ---------------- k2: out/upd GEMM, split-K across 4 waves, + transforms (round-4 form) ----------------
__global__ __launch_bounds__(256) void k2_outupd(
    const float* __restrict__ hTn,
    const float* __restrict__ Wout, const float* __restrict__ bout,
    const float* __restrict__ Wupd, const float* __restrict__ bupd,
    float* __restrict__ out,
    float* __restrict__ kvec_t, float* __restrict__ beta, float* __restrict__ gbuf,
    float* __restrict__ gam, float* __restrict__ shraw,
    float* __restrict__ erase, float* __restrict__ addb, int t)
{
  __shared__ float part[4][8][BB];
  int tid = threadIdx.x, ks = tid>>6, lane = tid&63;
  int c0 = blockIdx.x*8;
  bool isout = (c0 < DBX);
  size_t strd = isout ? (size_t)DBX : (size_t)(NH*PPH);
  const float* wbase = isout ? (Wout + c0) : (Wupd + (c0 - DBX));
  bool valid = (c0 < NCOLS);

  float acc[8] = {0,0,0,0,0,0,0,0};
  if (valid){
    int k0 = ks*128;
    #pragma unroll 4
    for (int k=k0; k<k0+128; ++k){
      float a = hTn[k*BB + lane];
      const float4* w4 = (const float4*)(wbase + (size_t)k*strd);
      float4 wa = w4[0], wb = w4[1];
      acc[0]+=a*wa.x; acc[1]+=a*wa.y; acc[2]+=a*wa.z; acc[3]+=a*wa.w;
      acc[4]+=a*wb.x; acc[5]+=a*wb.y; acc[6]+=a*wb.z; acc[7]+=a*wb.w;
    }
  }
  #pragma unroll
  for (int u=0; u<8; ++u) part[ks][u][lane] = acc[u];
  __syncthreads();
  if (!valid) return;

  for (int idx=tid; idx<8*BB; idx+=256){
    int u = idx>>6, b = idx&63;
    int c = c0+u;
    float v = part[0][u][b] + part[1][u][b] + part[2][u][b] + part[3][u][b];
    if (isout){
      out[((size_t)b*TT + t)*DBX + c] = sigmf(v + bout[c]);
    } else {
      int u2 = c - DBX;
      int hh = u2 / PPH;
      int p  = u2 - hh*PPH;
      v += bupd[u2];
      if (p < MMM)            kvec_t[b*HS + p*NH + hh] = v;
      else if (p == MMM)      beta[b*NH+hh] = softplusf(v);
      else if (p == MMM+1)    gbuf[b*NH+hh] = sigmf(v);
      else if (p <  MMM+5)    shraw[(b*NH+hh)*3 + (p-(MMM+2))] = v;
      else if (p == MMM+5)    gam[b*NH+hh] = 1.0f + softplusf(v);
      else if (p <  2*MMM+6)  erase[b*HS + hh*MMM + (p-(MMM+6))] = sigmf(v);
      else                    addb[b*HS + hh*MMM + (p-(2*MMM+6))] = tanhf(v);
    }
  }
}

// ---------------- dots partial: 32 m-rows per block ----------------
// grid (BB, 4, 4): s = a-chunk, z = m-chunk
__global__ __launch_bounds__(512) void k_dotsP(
    const float* __restrict__ mem, const float* __restrict__ kvec_t,
    float* __restrict__ dpart, float* __restrict__ n2part)
{
  int b = blockIdx.x, s = blockIdx.y, z = blockIdx.z, tid = threadIdx.x;
  __shared__ __align__(16) float klt[128];  // 32 rows x 4 heads, [m][h]
  if (tid < 128) klt[tid] = kvec_t[b*HS + z*128 + tid];
  __syncthreads();
  int a = s*512 + tid;
  const float* mp = mem + (size_t)b*MMM*AAA + (size_t)(z*32)*AAA + a;
  const float4* k4 = (const float4*)klt;
  float a0=0,a1=0,a2=0,a3=0,n2=0;
  #pragma unroll 8
  for (int m=0; m<32; ++m){
    float mv = mp[(size_t)m*AAA];
    float4 kv = k4[m];
    a0 += kv.x*mv; a1 += kv.y*mv; a2 += kv.z*mv; a3 += kv.w*mv;
    n2 += mv*mv;
  }
  size_t base = ((size_t)(z*BB+b)*NH)*AAA + a;
  dpart[base]        = a0;
  dpart[base+AAA]    = a1;
  dpart[base+2*AAA]  = a2;
  dpart[base+3*AAA]  = a3;
  n2part[(size_t)(z*BB+b)*AAA + a] = n2;
}

// ---------------- dots finalize: knorm + sim + exp + wcsum ----------------
__global__ __launch_bounds__(512) void k_dotsF(
    const float* __restrict__ dpart, const float* __restrict__ n2part,
    const float* __restrict__ kvec_t, const float* __restrict__ beta,
    float* __restrict__ ebuf, float* __restrict__ wcsum)
{
  int b = blockIdx.x, s = blockIdx.y, tid = threadIdx.x;
  __shared__ float red[HS];
  __shared__ float kn[NH];
  __shared__ float rsum[8*NH];
  float kv = kvec_t[b*HS + tid];
  red[tid] = kv*kv;
  __syncthreads();
  #pragma unroll
  for (int off=256; off>=4; off>>=1){
    if (tid < off) red[tid] += red[tid+off];
    __syncthreads();
  }
  if (tid < NH) kn[tid] = sqrtf(red[tid]);
  __syncthreads();

  int a = s*512 + tid;
  float d[NH] = {0,0,0,0};
  float n2 = 0.0f;
  #pragma unroll
  for (int z=0; z<4; ++z){
    size_t base = ((size_t)(z*BB+b)*NH)*AAA + a;
    d[0] += dpart[base];
    d[1] += dpart[base+AAA];
    d[2] += dpart[base+2*AAA];
    d[3] += dpart[base+3*AAA];
    n2   += n2part[(size_t)(z*BB+b)*AAA + a];
  }
  float mn = sqrtf(n2);
  int wid = tid >> 6, lane = tid & 63;
  #pragma unroll
  for (int hh=0; hh<NH; ++hh){
    float sim = d[hh]/(kn[hh]*mn + EPSF);
    float e = expf(beta[b*NH+hh]*sim);
    ebuf[((size_t)(b*NH+hh))*AAA + a] = e;
    float v = e;
    #pragma unroll
    for (int off=32; off>0; off>>=1) v += __shfl_xor(v, off);
    if (lane==0) rsum[wid*NH+hh] = v;
  }
  __syncthreads();
  if (tid < NH){
    float s2 = 0.0f;
    #pragma unroll
    for (int w=0; w<8; ++w) s2 += rsum[w*NH+tid];
    atomicAdd(&wcsum[b*NH+tid], s2);
  }
}

// ---------------- normalize + interpolate + shift + sharpen (round-4 form) ----------------
__global__ __launch_bounds__(512) void k_shift(
    const float* __restrict__ ebuf, const float* __restrict__ wcsum,
    const float* __restrict__ gbuf, const float* __restrict__ shraw,
    const float* __restrict__ gam, const float* __restrict__ wt,
    float* __restrict__ wpb, float* __restrict__ wpsum)
{
  int b = blockIdx.x, s = blockIdx.y, tid = threadIdx.x;
  int a = s*512 + tid;
  int am1 = (a + AAA - 1) & (AAA-1);
  int ap1 = (a + 1) & (AAA-1);
  __shared__ float sh[NH*3], gl[NH], gml[NH], winv[NH];
  __shared__ float rsum[8*NH];
  if (tid < NH){
    int hh = tid;
    float s0=shraw[(b*NH+hh)*3], s1=shraw[(b*NH+hh)*3+1], s2=shraw[(b*NH+hh)*3+2];
    float mx = fmaxf(s0, fmaxf(s1, s2));
    float e0=expf(s0-mx), e1=expf(s1-mx), e2=expf(s2-mx);
    float inv = 1.0f/(e0+e1+e2);
    sh[hh*3+0]=e0*inv; sh[hh*3+1]=e1*inv; sh[hh*3+2]=e2*inv;
    gl[hh]  = gbuf[b*NH+hh];
    gml[hh] = gam[b*NH+hh];
    winv[hh]= 1.0f/wcsum[b*NH+hh];
  }
  __syncthreads();
  int wid = tid >> 6, lane = tid & 63;
  #pragma unroll
  for (int hh=0; hh<NH; ++hh){
    const float* eb = ebuf + ((size_t)(b*NH+hh))*AAA;
    const float* wb = wt   + ((size_t)(b*NH+hh))*AAA;
    float inv = winv[hh], g = gl[hh];
    float s0 = sh[hh*3+0], s1 = sh[hh*3+1], s2 = sh[hh*3+2];
    float wgm1 = g*eb[am1]*inv + (1.0f-g)*wb[am1];
    float wg0  = g*eb[a]  *inv + (1.0f-g)*wb[a];
    float wgp1 = g*eb[ap1]*inv + (1.0f-g)*wb[ap1];
    float ws = s0*wgp1 + s1*wg0 + s2*wgm1;
    float wp = powf(ws + EPSF, gml[hh]);
    wpb[((size_t)(b*NH+hh))*AAA + a] = wp;
    float v = wp;
    #pragma unroll
    for (int off=32; off>0; off>>=1) v += __shfl_xor(v, off);
    if (lane==0) rsum[wid*NH+hh] = v;
  }
  __syncthreads();
  if (tid < NH){
    float s3 = 0.0f;
    #pragma unroll
    for (int w=0; w<8; ++w) s3 += rsum[w*NH+tid];
    atomicAdd(&wpsum[b*NH+tid], s3);
  }
}

// ---------------- updA: wt_new + mem erase/add over 32 m-rows ----------------
// grid (BB, 4, 4): s = a-chunk, z = m-chunk
__global__ __launch_bounds__(512) void k_updA(
    float* __restrict__ mem, const float* __restrict__ wpb, const float* __restrict__ wpsum,
    const float* __restrict__ erase, const float* __restrict__ addb,
    float* __restrict__ wt)
{
  int b = blockIdx.x, s = blockIdx.y, z = blockIdx.z, tid = threadIdx.x;
  int a = s*512 + tid;
  __shared__ __align__(16) float ert[128];   // 32 rows x 4 heads, [m][h]
  __shared__ __align__(16) float adt[128];
  if (tid < 128){
    int m = tid >> 2, hh = tid & 3;
    ert[tid] = erase[b*HS + hh*MMM + z*32 + m];
    adt[tid] = addb [b*HS + hh*MMM + z*32 + m];
  }
  float wtn[NH];
  #pragma unroll
  for (int hh=0; hh<NH; ++hh){
    float w = wpb[((size_t)(b*NH+hh))*AAA + a] / wpsum[b*NH+hh];
    wtn[hh] = w;
    if (z == 0) wt[((size_t)(b*NH+hh))*AAA + a] = w;
  }
  __syncthreads();

  float* mp = mem + (size_t)b*MMM*AAA + (size_t)(z*32)*AAA + a;
  const float4* e4 = (const float4*)ert;
  const float4* a4 = (const float4*)adt;
  #pragma unroll 8
  for (int m=0; m<32; ++m){
    float mv = mp[(size_t)m*AAA];
    float4 ev = e4[m], av = a4[m];
    float et = (1.0f - ev.x*wtn[0]) * (1.0f - ev.y*wtn[1])
             * (1.0f - ev.z*wtn[2]) * (1.0f - ev.w*wtn[3]);
    float at = av.x*wtn[0] + av.y*wtn[1] + av.z*wtn[2] + av.w*wtn[3];
    mp[(size_t)m*AAA] = mv*et + at;
  }
}

// ---------------- updB: read[b,h,m] einsum, wave owns rows m and m+64 ----------------
// grid (BB, 8), block 512 = 8 waves
__global__ __launch_bounds__(512) void k_updB(
    const float* __restrict__ mem, const float* __restrict__ wt,
    float* __restrict__ readTn)
{
  int b = blockIdx.x, my = blockIdx.y, tid = threadIdx.x;
  int wave = tid >> 6, lane = tid & 63;
  int m0 = my*8 + wave;         // 0..63
  int m1 = m0 + 64;             // 64..127
  const float* row0 = mem + (size_t)b*MMM*AAA + (size_t)m0*AAA;
  const float* row1 = mem + (size_t)b*MMM*AAA + (size_t)m1*AAA;
  const float* w0 = wt + ((size_t)(b*NH+0))*AAA;
  const float* w1 = wt + ((size_t)(b*NH+1))*AAA;
  const float* w2 = wt + ((size_t)(b*NH+2))*AAA;
  const float* w3 = wt + ((size_t)(b*NH+3))*AAA;
  float r00=0,r01=0,r02=0,r03=0, r10=0,r11=0,r12=0,r13=0;
  #pragma unroll 4
  for (int it=0; it<32; ++it){
    int a = it*64 + lane;
    float mv0 = row0[a], mv1 = row1[a];
    float wv0 = w0[a], wv1 = w1[a], wv2 = w2[a], wv3 = w3[a];
    r00 += mv0*wv0; r01 += mv0*wv1; r02 += mv0*wv2; r03 += mv0*wv3;
    r10 += mv1*wv0; r11 += mv1*wv1; r12 += mv1*wv2; r13 += mv1*wv3;
  }
  float rr[2][NH] = {{r00,r01,r02,r03},{r10,r11,r12,r13}};
  #pragma unroll
  for (int q=0; q<2; ++q){
    #pragma unroll
    for (int hh=0; hh<NH; ++hh){
      float v = rr[q][hh];
      #pragma unroll
      for (int off=32; off>0; off>>=1) v += __shfl_xor(v, off);
      rr[q][hh] = v;
    }
  }
  if (lane == 0){
    #pragma unroll
    for (int hh=0; hh<NH; ++hh){
      readTn[(size_t)(hh*MMM+m0)*BB + b] = rr[0][hh];
      readTn[(size_t)(hh*MMM+m1)*BB + b] = rr[1][hh];
    }
  }
}

extern "C" void kernel_launch(void* const* d_in, const int* in_sizes, int n_in,
                              void* d_out, int out_size, void* d_ws, size_t ws_size,
                              hipStream_t stream){
  const float* x    = (const float*)d_in[0];
  const float* Wst  = (const float*)d_in[1];
  const float* bst  = (const float*)d_in[2];
  const float* Wout = (const float*)d_in[3];
  const float* bout = (const float*)d_in[4];
  const float* Wupd = (const float*)d_in[5];
  const float* bupd = (const float*)d_in[6];
  float* out = (float*)d_out;

  float* p = (float*)d_ws;
  float* hT     = p; p += 2*HS*BB;            // ping-pong h, [j][b]
  float* readT  = p; p += 2*HS*BB;            // ping-pong read, [(h,m)][b]
  float* hpart  = p; p += KSPL*HS*BB;         // split-K partials (1 MB)
  float* xT     = p; p += (size_t)TT*IND*BB;  // transposed x (8.65 MB)
  float* wt     = p; p += BB*NH*AAA;
  float* mem    = p; p += (size_t)BB*MMM*AAA;
  float* kvec_t = p; p += BB*HS;
  float* beta   = p; p += BB*NH;
  float* gbuf   = p; p += BB*NH;
  float* gam    = p; p += BB*NH;
  float* shraw  = p; p += BB*NH*3;
  float* erase  = p; p += BB*HS;
  float* addb   = p; p += BB*HS;
  float* ebuf   = p; p += BB*NH*AAA;
  float* wpb    = p; p += 4*BB*NH*AAA;        // 8.4 MB: doubles as k_dots dpart (dead outside k_shift->k_updA window)
  float* n2part = p; p += 4*BB*AAA;           // 2 MB
  float* wcsum  = p; p += BB*NH;
  float* wpsum  = p; p += BB*NH;
  float* dpart  = wpb;                        // alias: dpart consumed before wpb written

  k_init<<<2048, 256, 0, stream>>>(hT, readT, wt, mem);
  k_tx<<<BB, 256, 0, stream>>>(x, xT);
  for (int t=0; t<TT; ++t){
    const float* hTp = hT    + (t&1)*HS*BB;
    float* hTn       = hT    + ((t+1)&1)*HS*BB;
    const float* rTp = readT + (t&1)*HS*BB;
    float* rTn       = readT + ((t+1)&1)*HS*BB;
    k1_state<<<dim3(32,KSPL), 256, 0, stream>>>(xT, Wst, hTp, rTp, hpart, wcsum, wpsum, t);
    k2h<<<64, 512, 0, stream>>>(hpart, bst, hTn);
    k2_outupd<<<dim3(259), 256, 0, stream>>>(hTn, Wout, bout, Wupd, bupd, out,
        kvec_t, beta, gbuf, gam, shraw, erase, addb, t);
    k_dotsP<<<dim3(BB,4,4), 512, 0, stream>>>(mem, kvec_t, dpart, n2part);
    k_dotsF<<<dim3(BB,4), 512, 0, stream>>>(dpart, n2part, kvec_t, beta, ebuf, wcsum);
    k_shift<<<dim3(BB,4), 512, 0, stream>>>(ebuf, wcsum, gbuf, shraw, gam, wt, wpb, wpsum);
    k_updA<<<dim3(BB,4,4), 512, 0, stream>>>(mem, wpb, wpsum, erase, addb, wt);
    k_updB<<<dim3(BB,8), 512, 0, stream>>>(mem, wt, rTn);
  }
}